// Round 2
// baseline (611.969 us; speedup 1.0000x reference)
//
#include <hip/hip_runtime.h>

typedef __bf16 bf16_t;
typedef __bf16 bf16x8 __attribute__((ext_vector_type(8)));
typedef __bf16 bf16x4 __attribute__((ext_vector_type(4)));
typedef __bf16 bf16x2 __attribute__((ext_vector_type(2)));
typedef float  f32x4  __attribute__((ext_vector_type(4)));

#define MFMA16(a, b, c) __builtin_amdgcn_mfma_f32_16x16x32_bf16((a), (b), (c), 0, 0, 0)

// ---------------------------------------------------------------------------
// Fused weight prep: all 8 matrices in one launch.
// W [Kact,128] f32 row-major -> bf16 MFMA-B-fragment-sequential.
// ---------------------------------------------------------------------------
__global__ __launch_bounds__(256) void prep_all_kernel(
    const float* __restrict__ nw,  const float* __restrict__ ew1,
    const float* __restrict__ ew2, const float* __restrict__ cw1,
    const float* __restrict__ cw2,
    bf16_t* __restrict__ nwt,  bf16_t* __restrict__ ew1t,
    bf16_t* __restrict__ ew2t, bf16_t* __restrict__ cw1t,
    bf16_t* __restrict__ cw2t)
{
    int b = blockIdx.x;
    const float* W; bf16_t* O; int Kact, KP, lb;
    if (b < 16)       { W = nw;  O = nwt;  Kact = 32;  KP = 32;  lb = b; }
    else if (b < 32)  { W = ew1; O = ew1t; Kact = 16;  KP = 32;  lb = b - 16; }
    else if (b < 96)  { W = ew2; O = ew2t; Kact = 128; KP = 128; lb = b - 32; }
    else if (b < 288) { int l = (b - 96) / 64;  W = cw1 + l * 16384; O = cw1t + l * 16384;
                        Kact = 128; KP = 128; lb = (b - 96) % 64; }
    else              { int l = (b - 288) / 64; W = cw2 + l * 16384; O = cw2t + l * 16384;
                        Kact = 128; KP = 128; lb = (b - 288) % 64; }
    int idx = lb * 256 + threadIdx.x;
    if (idx >= 128 * KP) return;
    int j    = idx & 7;
    int lane = (idx >> 3) & 63;
    int ct   = (idx >> 9) & 7;
    int kc   = idx >> 12;
    int n = ct * 16 + (lane & 15);
    int k = kc * 32 + (lane >> 4) * 8 + j;
    O[idx] = (bf16_t)((k < Kact) ? W[k * 128 + n] : 0.0f);
}

// ---------------------------------------------------------------------------
// CSR build. hist also WARMS edge_attr into the memory-side MALL (L3):
// one pass of sequential touches so edge_mlp's random 64B gathers hit L3,
// not DRAM (random 64B DRAM reads interleaved with the streaming write were
// the 2.2 TB/s limiter).
// ---------------------------------------------------------------------------
__global__ __launch_bounds__(256) void hist_kernel(const int* __restrict__ ei,
                                                   int* __restrict__ deg, int E,
                                                   const float* __restrict__ ea) {
    int t = blockIdx.x * 256 + threadIdx.x;
    if (t < E) {
        atomicAdd(&deg[ei[(long)E + t]], 1);
        float w0 = ea[(long)t * 16];
        float w1 = ea[(long)t * 16 + 8];
        asm volatile("" :: "v"(w0), "v"(w1));
    }
}

__global__ __launch_bounds__(256) void scanA_kernel(const int* __restrict__ deg,
                                                    int* __restrict__ partials,
                                                    int* __restrict__ bsums, int N) {
    __shared__ int s[256];
    int b = blockIdx.x, t = threadIdx.x;
    int base = b * 1024 + t * 4;
    int v0 = (base + 0 < N) ? deg[base + 0] : 0;
    int v1 = (base + 1 < N) ? deg[base + 1] : 0;
    int v2 = (base + 2 < N) ? deg[base + 2] : 0;
    int v3 = (base + 3 < N) ? deg[base + 3] : 0;
    int local = v0 + v1 + v2 + v3;
    s[t] = local;
    __syncthreads();
    for (int off = 1; off < 256; off <<= 1) {
        int v = (t >= off) ? s[t - off] : 0;
        __syncthreads();
        s[t] += v;
        __syncthreads();
    }
    int excl = s[t] - local;
    if (base + 0 < N) partials[base + 0] = excl;
    if (base + 1 < N) partials[base + 1] = excl + v0;
    if (base + 2 < N) partials[base + 2] = excl + v0 + v1;
    if (base + 3 < N) partials[base + 3] = excl + v0 + v1 + v2;
    if (t == 255) bsums[b] = s[255];
}

__global__ __launch_bounds__(256) void scanB_kernel(const int* __restrict__ bsums,
                                                    int* __restrict__ boff,
                                                    int* __restrict__ rowptr,
                                                    int NB, int N) {
    __shared__ int s[256];
    int t = threadIdx.x;
    int local = (t < NB) ? bsums[t] : 0;
    s[t] = local;
    __syncthreads();
    for (int off = 1; off < 256; off <<= 1) {
        int v = (t >= off) ? s[t - off] : 0;
        __syncthreads();
        s[t] += v;
        __syncthreads();
    }
    if (t < NB) boff[t] = s[t] - local;
    if (t == NB - 1) rowptr[N] = s[t];
}

__global__ __launch_bounds__(256) void scanC_kernel(const int* __restrict__ partials,
                                                    const int* __restrict__ boff,
                                                    int* __restrict__ rowptr,
                                                    int* __restrict__ cursor, int N) {
    int i = blockIdx.x * 256 + threadIdx.x;
    if (i >= N) return;
    int v = partials[i] + boff[i >> 10];
    rowptr[i] = v;
    cursor[i] = v;
}

__global__ __launch_bounds__(256) void scatter_kernel(const int* __restrict__ ei,
                                                      int* __restrict__ cursor,
                                                      int* __restrict__ srcp,
                                                      int* __restrict__ eorig, int E) {
    int t = blockIdx.x * 256 + threadIdx.x;
    if (t >= E) return;
    int d = ei[(long)E + t];
    int pos = atomicAdd(&cursor[d], 1);
    srcp[pos] = ei[t];
    eorig[pos] = t;
}

// ---------------------------------------------------------------------------
// Node encoder: h = x[M,32] @ W + bias, out bf16. Barrier-free wave-private.
// ---------------------------------------------------------------------------
__global__ __launch_bounds__(256) void node_enc_kernel(
    const float* __restrict__ A, int M,
    const bf16_t* __restrict__ Ws, const float* __restrict__ bias,
    bf16_t* __restrict__ outp)
{
    constexpr int S = 136;
    __shared__ bf16_t T[128 * S];

    const int  tid  = threadIdx.x;
    const int  wv   = tid >> 6, lane = tid & 63;
    const long row0 = (long)blockIdx.x * 128;
    const int  l16  = lane & 15, quad = lane >> 4;

    {
        int r  = wv * 32 + (lane >> 1);
        long gr = row0 + r;
        int c0 = (lane & 1) * 16;
#pragma unroll
        for (int q = 0; q < 4; ++q) {
            float4 v = make_float4(0.f, 0.f, 0.f, 0.f);
            if (gr < M) v = *(const float4*)(A + gr * 32 + c0 + q * 4);
            bf16_t* d = &T[r * S + c0 + q * 4];
            d[0] = (bf16_t)v.x; d[1] = (bf16_t)v.y; d[2] = (bf16_t)v.z; d[3] = (bf16_t)v.w;
        }
    }

    f32x4 acc[2][8];
#pragma unroll
    for (int r = 0; r < 2; r++)
#pragma unroll
        for (int c = 0; c < 8; c++) acc[r][c] = (f32x4){0.f, 0.f, 0.f, 0.f};

    {
        bf16x8 af0 = *(const bf16x8*)&T[(wv * 32 + l16) * S + quad * 8];
        bf16x8 af1 = *(const bf16x8*)&T[(wv * 32 + 16 + l16) * S + quad * 8];
#pragma unroll
        for (int c = 0; c < 8; c++) {
            bf16x8 bfr = *(const bf16x8*)&Ws[((c * 64) + lane) * 8];
            acc[0][c] = MFMA16(af0, bfr, acc[0][c]);
            acc[1][c] = MFMA16(af1, bfr, acc[1][c]);
        }
    }

#pragma unroll
    for (int r = 0; r < 2; r++) {
        int mrow = wv * 32 + r * 16 + quad * 4;
#pragma unroll
        for (int c = 0; c < 8; c++) {
            int col = c * 16 + l16;
            float bb = bias[col];
#pragma unroll
            for (int q = 0; q < 4; q++)
                T[(mrow + q) * S + col] = (bf16_t)(acc[r][c][q] + bb);
        }
    }

#pragma unroll
    for (int it = 0; it < 8; ++it) {
        int idx = it * 64 + lane;
        int row = wv * 32 + (idx >> 4);
        int seg = idx & 15;
        long grow = row0 + row;
        if (grow < M)
            *(uint4*)&outp[grow * 128 + seg * 8] = *(const uint4*)&T[row * S + seg * 8];
    }
}

// ---------------------------------------------------------------------------
// Fused edge encoder, 64-row tiles, barrier-free wave-private flow.
// Random gathers now hit the warmed MALL.
// ---------------------------------------------------------------------------
__global__ __launch_bounds__(256) void edge_mlp_kernel(
    const float* __restrict__ A, int M,
    const bf16_t* __restrict__ Ws1, const float* __restrict__ b1,
    const bf16_t* __restrict__ Ws2, const float* __restrict__ b2,
    const int* __restrict__ eorig, bf16_t* __restrict__ outp)
{
    constexpr int S = 136;
    __shared__ bf16_t T[64 * S];

    const int  tid  = threadIdx.x;
    const int  wv   = tid >> 6, lane = tid & 63;
    const long row0 = (long)blockIdx.x * 64;
    const int  l16  = lane & 15, quad = lane >> 4;

    {
        int  r  = wv * 16 + (lane >> 2);
        long gr = row0 + r;
        float4 v = make_float4(0.f, 0.f, 0.f, 0.f);
        if (gr < M) {
            long eo = eorig[gr];
            v = *(const float4*)(A + eo * 16 + (lane & 3) * 4);
        }
        bf16_t* d = &T[r * S + (lane & 3) * 4];
        d[0] = (bf16_t)v.x; d[1] = (bf16_t)v.y; d[2] = (bf16_t)v.z; d[3] = (bf16_t)v.w;
    }

    f32x4 acc[8];
#pragma unroll
    for (int c = 0; c < 8; c++) acc[c] = (f32x4){0.f, 0.f, 0.f, 0.f};

    {   // stage 1: K=16
        bf16x8 af;
#pragma unroll
        for (int j = 0; j < 8; ++j) af[j] = (bf16_t)0.f;
        if (quad < 2) af = *(const bf16x8*)&T[(wv * 16 + l16) * S + quad * 8];
#pragma unroll
        for (int c = 0; c < 8; c++) {
            bf16x8 bfr = *(const bf16x8*)&Ws1[((c * 64) + lane) * 8];
            acc[c] = MFMA16(af, bfr, acc[c]);
        }
    }

    const int mbase = wv * 16 + quad * 4;

#pragma unroll
    for (int c = 0; c < 8; c++) {
        int col = c * 16 + l16;
        float bb = b1[col];
#pragma unroll
        for (int q = 0; q < 4; q++)
            T[(mbase + q) * S + col] = (bf16_t)fmaxf(acc[c][q] + bb, 0.f);
    }

#pragma unroll
    for (int c = 0; c < 8; c++) acc[c] = (f32x4){0.f, 0.f, 0.f, 0.f};

#pragma unroll
    for (int kc = 0; kc < 4; ++kc) {   // stage 2: K=128
        bf16x8 af = *(const bf16x8*)&T[(wv * 16 + l16) * S + kc * 32 + quad * 8];
#pragma unroll
        for (int c = 0; c < 8; c++) {
            bf16x8 bfr = *(const bf16x8*)&Ws2[(((kc * 8 + c) * 64) + lane) * 8];
            acc[c] = MFMA16(af, bfr, acc[c]);
        }
    }

#pragma unroll
    for (int c = 0; c < 8; c++) {
        int col = c * 16 + l16;
        float bb = b2[col];
#pragma unroll
        for (int q = 0; q < 4; q++)
            T[(mbase + q) * S + col] = (bf16_t)(acc[c][q] + bb);
    }

#pragma unroll
    for (int it = 0; it < 4; ++it) {
        int idx = it * 64 + lane;
        int row = wv * 16 + (idx >> 4);
        int seg = idx & 15;
        long grow = row0 + row;
        if (grow < M)
            *(uint4*)&outp[grow * 128 + seg * 8] = *(const uint4*)&T[row * S + seg * 8];
    }
}

// ---------------------------------------------------------------------------
// FUSED BN(+relu) + aggregation + GINEConv MLP, 64-node tiles, barrier-free
// (one barrier only for cross-wave BN stats at the end).
// NEW: two independent rows per wave (half-wave per row, 4 cols/lane, 8B
// loads) -> half the gather instructions, 2 independent load chains/wave.
// BN sc/sh derived inline from previous layer's bn_sums slot (bn_fin fused).
// ---------------------------------------------------------------------------
template <int BN>
__global__ __launch_bounds__(256) void aggr_conv_kernel(
    const bf16_t* __restrict__ xin,
    const float* __restrict__ bns_prev,
    const float* __restrict__ gamma, const float* __restrict__ beta,
    const bf16_t* __restrict__ e,
    const int* __restrict__ rowptr, const int* __restrict__ srcp, int M,
    const bf16_t* __restrict__ Ws1, const float* __restrict__ b1,
    const bf16_t* __restrict__ Ws2, const float* __restrict__ b2,
    bf16_t* __restrict__ zout, float* __restrict__ bn_out)
{
    constexpr int S = 136;
    __shared__ bf16_t T[64 * S];

    const int  tid  = threadIdx.x;
    const int  wv   = tid >> 6, lane = tid & 63;
    const int  half = lane >> 5, l32 = lane & 31;
    const int  c0   = l32 * 4;
    const long row0 = (long)blockIdx.x * 64;

    float sc[4], sh[4];
    if (BN) {
#pragma unroll
        for (int u = 0; u < 4; ++u) {
            int c = c0 + u;
            float mean = bns_prev[c] / (float)M;
            float var  = bns_prev[128 + c] / (float)M - mean * mean;
            float inv  = rsqrtf(var + 1e-5f);
            sc[u] = gamma[c] * inv;
            sh[u] = beta[c] - mean * sc[u];
        }
    }

    // --- gather + aggregate: 8 row-pairs per wave, one row per half-wave ---
#pragma unroll 1
    for (int rp = 0; rp < 8; ++rp) {
        int  rA = wv * 16 + rp * 2;
        long n  = row0 + rA + half;
        float a0 = 0.f, a1 = 0.f, a2 = 0.f, a3 = 0.f;
        int beg = 0, cnt = 0;
        if (n < M) {
            beg = rowptr[n];
            cnt = rowptr[n + 1] - beg;
            bf16x4 xv = *(const bf16x4*)(xin + n * 128 + c0);
            if (BN) {
                a0 = fmaxf((float)xv[0] * sc[0] + sh[0], 0.f);
                a1 = fmaxf((float)xv[1] * sc[1] + sh[1], 0.f);
                a2 = fmaxf((float)xv[2] * sc[2] + sh[2], 0.f);
                a3 = fmaxf((float)xv[3] * sc[3] + sh[3], 0.f);
            } else {
                a0 = (float)xv[0]; a1 = (float)xv[1];
                a2 = (float)xv[2]; a3 = (float)xv[3];
            }
        }
        for (int cb = 0;; cb += 32) {
            int rem = cnt - cb;
            int mx  = max(rem, __shfl_xor(rem, 32));
            if (mx <= 0) break;
            int sv   = (cb + l32 < cnt) ? srcp[beg + cb + l32] : 0;
            int ccnt = min(rem, 32);
            int lim  = min(mx, 32);
            for (int j = 0; j < lim; j += 4) {
                int ib = (half << 5) + j;
                int s0 = __shfl(sv, ib),     s1 = __shfl(sv, ib + 1);
                int s2 = __shfl(sv, ib + 2), s3 = __shfl(sv, ib + 3);
                bool v0 = j < ccnt, v1 = j + 1 < ccnt, v2 = j + 2 < ccnt, v3 = j + 3 < ccnt;
                long eb = (long)(beg + cb + j);
                bf16x4 x0 = *(const bf16x4*)(xin + (long)s0 * 128 + c0);
                bf16x4 x1 = *(const bf16x4*)(xin + (long)s1 * 128 + c0);
                bf16x4 x2 = *(const bf16x4*)(xin + (long)s2 * 128 + c0);
                bf16x4 x3 = *(const bf16x4*)(xin + (long)s3 * 128 + c0);
                bf16x4 e0 = *(const bf16x4*)(e + (v0 ? eb     : 0) * 128 + c0);
                bf16x4 e1 = *(const bf16x4*)(e + (v1 ? eb + 1 : 0) * 128 + c0);
                bf16x4 e2 = *(const bf16x4*)(e + (v2 ? eb + 2 : 0) * 128 + c0);
                bf16x4 e3 = *(const bf16x4*)(e + (v3 ? eb + 3 : 0) * 128 + c0);
#define ACC4(XV, EV, V)                                                        \
                do {                                                           \
                    float h0 = (float)XV[0], h1 = (float)XV[1];                \
                    float h2 = (float)XV[2], h3 = (float)XV[3];                \
                    if (BN) {                                                  \
                        h0 = fmaxf(h0 * sc[0] + sh[0], 0.f);                   \
                        h1 = fmaxf(h1 * sc[1] + sh[1], 0.f);                   \
                        h2 = fmaxf(h2 * sc[2] + sh[2], 0.f);                   \
                        h3 = fmaxf(h3 * sc[3] + sh[3], 0.f);                   \
                    }                                                          \
                    float t0 = fmaxf(h0 + (float)EV[0], 0.f);                  \
                    float t1 = fmaxf(h1 + (float)EV[1], 0.f);                  \
                    float t2 = fmaxf(h2 + (float)EV[2], 0.f);                  \
                    float t3 = fmaxf(h3 + (float)EV[3], 0.f);                  \
                    if (V) { a0 += t0; a1 += t1; a2 += t2; a3 += t3; }         \
                } while (0)
                ACC4(x0, e0, v0);
                ACC4(x1, e1, v1);
                ACC4(x2, e2, v2);
                ACC4(x3, e3, v3);
#undef ACC4
            }
        }
        bf16x4 o;
        o[0] = (bf16_t)a0; o[1] = (bf16_t)a1; o[2] = (bf16_t)a2; o[3] = (bf16_t)a3;
        *(bf16x4*)&T[(rA + half) * S + c0] = o;
    }

    const int l16 = lane & 15, quad = lane >> 4;
    const int mbase = wv * 16 + quad * 4;

    f32x4 acc[8];
#pragma unroll
    for (int c = 0; c < 8; c++) acc[c] = (f32x4){0.f, 0.f, 0.f, 0.f};

#pragma unroll
    for (int kc = 0; kc < 4; ++kc) {
        bf16x8 af = *(const bf16x8*)&T[(wv * 16 + l16) * S + kc * 32 + quad * 8];
#pragma unroll
        for (int c = 0; c < 8; c++) {
            bf16x8 bfr = *(const bf16x8*)&Ws1[(((kc * 8 + c) * 64) + lane) * 8];
            acc[c] = MFMA16(af, bfr, acc[c]);
        }
    }

#pragma unroll
    for (int c = 0; c < 8; c++) {
        int col = c * 16 + l16;
        float bb = b1[col];
#pragma unroll
        for (int q = 0; q < 4; q++)
            T[(mbase + q) * S + col] = (bf16_t)fmaxf(acc[c][q] + bb, 0.f);
    }

#pragma unroll
    for (int c = 0; c < 8; c++) acc[c] = (f32x4){0.f, 0.f, 0.f, 0.f};

#pragma unroll
    for (int kc = 0; kc < 4; ++kc) {
        bf16x8 af = *(const bf16x8*)&T[(wv * 16 + l16) * S + kc * 32 + quad * 8];
#pragma unroll
        for (int c = 0; c < 8; c++) {
            bf16x8 bfr = *(const bf16x8*)&Ws2[(((kc * 8 + c) * 64) + lane) * 8];
            acc[c] = MFMA16(af, bfr, acc[c]);
        }
    }

    float ssum[8], ssq[8];
#pragma unroll
    for (int c = 0; c < 8; c++) {
        int col = c * 16 + l16;
        float bb = b2[col];
        float s = 0.f, s2 = 0.f;
#pragma unroll
        for (int q = 0; q < 4; q++) {
            float v = acc[c][q] + bb;
            T[(mbase + q) * S + col] = (bf16_t)v;
            if (row0 + mbase + q < M) { s += v; s2 += v * v; }
        }
        s  += __shfl_xor(s, 16);  s  += __shfl_xor(s, 32);
        s2 += __shfl_xor(s2, 16); s2 += __shfl_xor(s2, 32);
        ssum[c] = s; ssq[c] = s2;
    }

#pragma unroll
    for (int it = 0; it < 4; ++it) {
        int idx = it * 64 + lane;
        int row = wv * 16 + (idx >> 4);
        int seg = idx & 15;
        long grow = row0 + row;
        if (grow < M)
            *(uint4*)&zout[grow * 128 + seg * 8] = *(const uint4*)&T[row * S + seg * 8];
    }

    float* wred = (float*)&T[(size_t)(wv * 16) * S];
    if (quad == 0) {
#pragma unroll
        for (int c = 0; c < 8; c++) {
            int col = c * 16 + l16;
            wred[col]       = ssum[c];
            wred[128 + col] = ssq[c];
        }
    }
    __syncthreads();
    if (tid < 128) {
        float s = 0.f, s2 = 0.f;
#pragma unroll
        for (int w = 0; w < 4; ++w) {
            const float* wr = (const float*)&T[(size_t)(w * 16) * S];
            s  += wr[tid];
            s2 += wr[128 + tid];
        }
        atomicAdd(&bn_out[tid], s);
        atomicAdd(&bn_out[128 + tid], s2);
    }
}

// ---------------------------------------------------------------------------
// Mean-pool over sorted batch; derives final-layer BN inline.
// ---------------------------------------------------------------------------
__global__ __launch_bounds__(128) void pool_kernel(
    const bf16_t* __restrict__ z, const float* __restrict__ bns,
    const float* __restrict__ gamma, const float* __restrict__ beta,
    const int* __restrict__ batch,
    float* __restrict__ gsum, float* __restrict__ cnt, int N)
{
    int c = threadIdx.x;
    float mean = bns[c] / (float)N;
    float var  = bns[128 + c] / (float)N - mean * mean;
    float inv  = rsqrtf(var + 1e-5f);
    float sc   = gamma[c] * inv;
    float sh   = beta[c] - mean * sc;
    int n0 = blockIdx.x * 32;
    int n1 = min(n0 + 32, N);
    float acc = 0.f;
    int cur = -1, rc = 0;
    for (int n = n0; n < n1; ++n) {
        int g = batch[n];
        if (g != cur) {
            if (cur >= 0) {
                atomicAdd(&gsum[(long)cur * 128 + c], acc);
                if (c == 0) atomicAdd(&cnt[cur], (float)rc);
            }
            cur = g; acc = 0.f; rc = 0;
        }
        acc += fmaxf((float)z[(long)n * 128 + c] * sc + sh, 0.f);
        rc++;
    }
    if (cur >= 0) {
        atomicAdd(&gsum[(long)cur * 128 + c], acc);
        if (c == 0) atomicAdd(&cnt[cur], (float)rc);
    }
}

__global__ __launch_bounds__(128) void head_kernel(
    const float* __restrict__ gsum, const float* __restrict__ cnt,
    const float* __restrict__ ext_in,
    const float* __restrict__ ew1, const float* __restrict__ eb1,
    const float* __restrict__ ew2, const float* __restrict__ eb2,
    const float* __restrict__ rw1, const float* __restrict__ rb1,
    const float* __restrict__ rw2, const float* __restrict__ rb2,
    float* __restrict__ out)
{
    int g = blockIdx.x, c = threadIdx.x;
    __shared__ float sx[8];
    __shared__ float h1[128];
    __shared__ float comb[256];
    __shared__ float red[128];

    if (c < 8) sx[c] = ext_in[g * 8 + c];
    __syncthreads();
    float a = eb1[c];
#pragma unroll
    for (int k = 0; k < 8; k++) a += sx[k] * ew1[k * 128 + c];
    h1[c] = fmaxf(a, 0.f);
    __syncthreads();
    float b = eb2[c];
    for (int k = 0; k < 128; k++) b += h1[k] * ew2[k * 128 + c];
    comb[c]       = gsum[(long)g * 128 + c] / fmaxf(cnt[g], 1.0f);
    comb[128 + c] = b;
    __syncthreads();
    float r = rb1[c];
    for (int k = 0; k < 256; k++) r += comb[k] * rw1[k * 128 + c];
    r = fmaxf(r, 0.f);
    red[c] = r * rw2[c];
    __syncthreads();
    if (c == 0) {
        float s = rb2[0];
        for (int k = 0; k < 128; k++) s += red[k];
        out[g] = s;
    }
}

// ---------------------------------------------------------------------------
extern "C" void kernel_launch(void* const* d_in, const int* in_sizes, int n_in,
                              void* d_out, int out_size, void* d_ws, size_t ws_size,
                              hipStream_t stream)
{
    const float* x         = (const float*)d_in[0];
    const float* edge_attr = (const float*)d_in[1];
    const float* externals = (const float*)d_in[2];
    const float* node_w    = (const float*)d_in[3];
    const float* node_b    = (const float*)d_in[4];
    const float* ee_w1     = (const float*)d_in[5];
    const float* ee_b1     = (const float*)d_in[6];
    const float* ee_w2     = (const float*)d_in[7];
    const float* ee_b2     = (const float*)d_in[8];
    const float* conv_w1   = (const float*)d_in[9];
    const float* conv_b1   = (const float*)d_in[10];
    const float* conv_w2   = (const float*)d_in[11];
    const float* conv_b2   = (const float*)d_in[12];
    const float* bn_gamma  = (const float*)d_in[13];
    const float* bn_beta   = (const float*)d_in[14];
    const float* ext_w1    = (const float*)d_in[15];
    const float* ext_b1    = (const float*)d_in[16];
    const float* ext_w2    = (const float*)d_in[17];
    const float* ext_b2    = (const float*)d_in[18];
    const float* reg_w1    = (const float*)d_in[19];
    const float* reg_b1    = (const float*)d_in[20];
    const float* reg_w2    = (const float*)d_in[21];
    const float* reg_b2    = (const float*)d_in[22];
    const int* edge_index  = (const int*)d_in[23];
    const int* batch       = (const int*)d_in[24];

    const int N = in_sizes[0] / 32;
    const int E = in_sizes[1] / 16;
    const int G = in_sizes[2] / 8;
    const int NB = (N + 1023) / 1024;

    char* p = (char*)d_ws;
    auto alloc = [&](size_t bytes) -> void* {
        void* r = (void*)p;
        p += (bytes + 255) & ~(size_t)255;
        return r;
    };
    bf16_t* h       = (bf16_t*)alloc((size_t)N * 128 * 2);
    bf16_t* zA      = (bf16_t*)alloc((size_t)N * 128 * 2);
    bf16_t* zB      = (bf16_t*)alloc((size_t)N * 128 * 2);
    bf16_t* ebuf    = (bf16_t*)alloc((size_t)E * 128 * 2);   // dst-sorted
    int*    deg     = (int*)alloc((size_t)N * 4);
    int*    rowptr  = (int*)alloc(((size_t)N + 1) * 4);
    int*    cursor  = (int*)alloc((size_t)N * 4);
    int*    partials= (int*)alloc((size_t)N * 4);
    int*    bsums   = (int*)alloc((size_t)NB * 4);
    int*    boff    = (int*)alloc((size_t)NB * 4);
    int*    srcp    = (int*)alloc((size_t)E * 4);
    int*    eorig   = (int*)alloc((size_t)E * 4);
    bf16_t* node_wt = (bf16_t*)alloc(128 * 32 * 2);
    bf16_t* ee_w1t  = (bf16_t*)alloc(128 * 32 * 2);
    bf16_t* ee_w2t  = (bf16_t*)alloc(128 * 128 * 2);
    bf16_t* cw1t    = (bf16_t*)alloc(3 * 128 * 128 * 2);
    bf16_t* cw2t    = (bf16_t*)alloc(3 * 128 * 128 * 2);
    float*  bns     = (float*)alloc(3 * 256 * 4);            // per-layer BN sums
    float*  gsum    = (float*)alloc((size_t)G * 128 * 4);
    float*  cnt     = (float*)alloc((size_t)G * 4);

    // --- CSR build (by dst); hist also warms edge_attr into MALL ---
    hipMemsetAsync(deg, 0, (size_t)N * 4, stream);
    hipMemsetAsync(bns, 0, 3 * 256 * 4, stream);
    hist_kernel<<<(E + 255) / 256, 256, 0, stream>>>(edge_index, deg, E, edge_attr);
    scanA_kernel<<<NB, 256, 0, stream>>>(deg, partials, bsums, N);
    scanB_kernel<<<1, 256, 0, stream>>>(bsums, boff, rowptr, NB, N);
    scanC_kernel<<<(N + 255) / 256, 256, 0, stream>>>(partials, boff, rowptr, cursor, N);
    scatter_kernel<<<(E + 255) / 256, 256, 0, stream>>>(edge_index, cursor, srcp, eorig, E);

    // --- weight prep (single launch) ---
    prep_all_kernel<<<480, 256, 0, stream>>>(node_w, ee_w1, ee_w2, conv_w1, conv_w2,
                                             node_wt, ee_w1t, ee_w2t, cw1t, cw2t);

    // --- node encoder ---
    node_enc_kernel<<<(N + 127) / 128, 256, 0, stream>>>(x, N, node_wt, node_b, h);

    // --- edge encoder, CSR-order compute, sequential write ---
    edge_mlp_kernel<<<(E + 63) / 64, 256, 0, stream>>>(
        edge_attr, E, ee_w1t, ee_b1, ee_w2t, ee_b2, eorig, ebuf);

    // --- GINE layers: BN folded into the gather of the next consumer ---
    const int nblk = (N + 63) / 64;
    aggr_conv_kernel<0><<<nblk, 256, 0, stream>>>(
        h, nullptr, nullptr, nullptr, ebuf, rowptr, srcp, N,
        cw1t + 0 * 16384, conv_b1 + 0 * 128, cw2t + 0 * 16384, conv_b2 + 0 * 128,
        zA, bns + 0);
    aggr_conv_kernel<1><<<nblk, 256, 0, stream>>>(
        zA, bns + 0, bn_gamma + 0, bn_beta + 0, ebuf, rowptr, srcp, N,
        cw1t + 1 * 16384, conv_b1 + 1 * 128, cw2t + 1 * 16384, conv_b2 + 1 * 128,
        zB, bns + 256);
    aggr_conv_kernel<1><<<nblk, 256, 0, stream>>>(
        zB, bns + 256, bn_gamma + 128, bn_beta + 128, ebuf, rowptr, srcp, N,
        cw1t + 2 * 16384, conv_b1 + 2 * 128, cw2t + 2 * 16384, conv_b2 + 2 * 128,
        zA, bns + 512);

    // --- pooling (BN+relu applied on read) + head ---
    hipMemsetAsync(gsum, 0, (size_t)G * 128 * 4, stream);
    hipMemsetAsync(cnt, 0, (size_t)G * 4, stream);
    pool_kernel<<<(N + 31) / 32, 128, 0, stream>>>(zA, bns + 512, bn_gamma + 256, bn_beta + 256,
                                                   batch, gsum, cnt, N);
    head_kernel<<<G, 128, 0, stream>>>(gsum, cnt, externals,
                                       ext_w1, ext_b1, ext_w2, ext_b2,
                                       reg_w1, reg_b1, reg_w2, reg_b2,
                                       (float*)d_out);
}

// Round 3
// 578.578 us; speedup vs baseline: 1.0577x; 1.0577x over previous
//
#include <hip/hip_runtime.h>

typedef __bf16 bf16_t;
typedef __bf16 bf16x8 __attribute__((ext_vector_type(8)));
typedef __bf16 bf16x4 __attribute__((ext_vector_type(4)));
typedef __bf16 bf16x2 __attribute__((ext_vector_type(2)));
typedef float  f32x4  __attribute__((ext_vector_type(4)));

#define MFMA16(a, b, c) __builtin_amdgcn_mfma_f32_16x16x32_bf16((a), (b), (c), 0, 0, 0)

// ---------------------------------------------------------------------------
// Fused weight prep: all 8 matrices in one launch.
// ---------------------------------------------------------------------------
__global__ __launch_bounds__(256) void prep_all_kernel(
    const float* __restrict__ nw,  const float* __restrict__ ew1,
    const float* __restrict__ ew2, const float* __restrict__ cw1,
    const float* __restrict__ cw2,
    bf16_t* __restrict__ nwt,  bf16_t* __restrict__ ew1t,
    bf16_t* __restrict__ ew2t, bf16_t* __restrict__ cw1t,
    bf16_t* __restrict__ cw2t)
{
    int b = blockIdx.x;
    const float* W; bf16_t* O; int Kact, KP, lb;
    if (b < 16)       { W = nw;  O = nwt;  Kact = 32;  KP = 32;  lb = b; }
    else if (b < 32)  { W = ew1; O = ew1t; Kact = 16;  KP = 32;  lb = b - 16; }
    else if (b < 96)  { W = ew2; O = ew2t; Kact = 128; KP = 128; lb = b - 32; }
    else if (b < 288) { int l = (b - 96) / 64;  W = cw1 + l * 16384; O = cw1t + l * 16384;
                        Kact = 128; KP = 128; lb = (b - 96) % 64; }
    else              { int l = (b - 288) / 64; W = cw2 + l * 16384; O = cw2t + l * 16384;
                        Kact = 128; KP = 128; lb = (b - 288) % 64; }
    int idx = lb * 256 + threadIdx.x;
    if (idx >= 128 * KP) return;
    int j    = idx & 7;
    int lane = (idx >> 3) & 63;
    int ct   = (idx >> 9) & 7;
    int kc   = idx >> 12;
    int n = ct * 16 + (lane & 15);
    int k = kc * 32 + (lane >> 4) * 8 + j;
    O[idx] = (bf16_t)((k < Kact) ? W[k * 128 + n] : 0.0f);
}

// ---------------------------------------------------------------------------
// CSR build; hist also warms edge_attr into the MALL.
// ---------------------------------------------------------------------------
__global__ __launch_bounds__(256) void hist_kernel(const int* __restrict__ ei,
                                                   int* __restrict__ deg, int E,
                                                   const float* __restrict__ ea) {
    int t = blockIdx.x * 256 + threadIdx.x;
    if (t < E) {
        atomicAdd(&deg[ei[(long)E + t]], 1);
        float w0 = ea[(long)t * 16];
        float w1 = ea[(long)t * 16 + 8];
        asm volatile("" :: "v"(w0), "v"(w1));
    }
}

__global__ __launch_bounds__(256) void scanA_kernel(const int* __restrict__ deg,
                                                    int* __restrict__ partials,
                                                    int* __restrict__ bsums, int N) {
    __shared__ int s[256];
    int b = blockIdx.x, t = threadIdx.x;
    int base = b * 1024 + t * 4;
    int v0 = (base + 0 < N) ? deg[base + 0] : 0;
    int v1 = (base + 1 < N) ? deg[base + 1] : 0;
    int v2 = (base + 2 < N) ? deg[base + 2] : 0;
    int v3 = (base + 3 < N) ? deg[base + 3] : 0;
    int local = v0 + v1 + v2 + v3;
    s[t] = local;
    __syncthreads();
    for (int off = 1; off < 256; off <<= 1) {
        int v = (t >= off) ? s[t - off] : 0;
        __syncthreads();
        s[t] += v;
        __syncthreads();
    }
    int excl = s[t] - local;
    if (base + 0 < N) partials[base + 0] = excl;
    if (base + 1 < N) partials[base + 1] = excl + v0;
    if (base + 2 < N) partials[base + 2] = excl + v0 + v1;
    if (base + 3 < N) partials[base + 3] = excl + v0 + v1 + v2;
    if (t == 255) bsums[b] = s[255];
}

__global__ __launch_bounds__(256) void scanB_kernel(const int* __restrict__ bsums,
                                                    int* __restrict__ boff,
                                                    int* __restrict__ rowptr,
                                                    int NB, int N) {
    __shared__ int s[256];
    int t = threadIdx.x;
    int local = (t < NB) ? bsums[t] : 0;
    s[t] = local;
    __syncthreads();
    for (int off = 1; off < 256; off <<= 1) {
        int v = (t >= off) ? s[t - off] : 0;
        __syncthreads();
        s[t] += v;
        __syncthreads();
    }
    if (t < NB) boff[t] = s[t] - local;
    if (t == NB - 1) rowptr[N] = s[t];
}

__global__ __launch_bounds__(256) void scanC_kernel(const int* __restrict__ partials,
                                                    const int* __restrict__ boff,
                                                    int* __restrict__ rowptr,
                                                    int* __restrict__ cursor, int N) {
    int i = blockIdx.x * 256 + threadIdx.x;
    if (i >= N) return;
    int v = partials[i] + boff[i >> 10];
    rowptr[i] = v;
    cursor[i] = v;
}

__global__ __launch_bounds__(256) void scatter_kernel(const int* __restrict__ ei,
                                                      int* __restrict__ cursor,
                                                      int* __restrict__ srcp,
                                                      int* __restrict__ eorig, int E) {
    int t = blockIdx.x * 256 + threadIdx.x;
    if (t >= E) return;
    int d = ei[(long)E + t];
    int pos = atomicAdd(&cursor[d], 1);
    srcp[pos] = ei[t];
    eorig[pos] = t;
}

// ---------------------------------------------------------------------------
// Node encoder: h = x[M,32] @ W + bias, out bf16. Barrier-free wave-private.
// ---------------------------------------------------------------------------
__global__ __launch_bounds__(256) void node_enc_kernel(
    const float* __restrict__ A, int M,
    const bf16_t* __restrict__ Ws, const float* __restrict__ bias,
    bf16_t* __restrict__ outp)
{
    constexpr int S = 136;
    __shared__ bf16_t T[128 * S];

    const int  tid  = threadIdx.x;
    const int  wv   = tid >> 6, lane = tid & 63;
    const long row0 = (long)blockIdx.x * 128;
    const int  l16  = lane & 15, quad = lane >> 4;

    {
        int r  = wv * 32 + (lane >> 1);
        long gr = row0 + r;
        int c0 = (lane & 1) * 16;
#pragma unroll
        for (int q = 0; q < 4; ++q) {
            float4 v = make_float4(0.f, 0.f, 0.f, 0.f);
            if (gr < M) v = *(const float4*)(A + gr * 32 + c0 + q * 4);
            bf16_t* d = &T[r * S + c0 + q * 4];
            d[0] = (bf16_t)v.x; d[1] = (bf16_t)v.y; d[2] = (bf16_t)v.z; d[3] = (bf16_t)v.w;
        }
    }

    f32x4 acc[2][8];
#pragma unroll
    for (int r = 0; r < 2; r++)
#pragma unroll
        for (int c = 0; c < 8; c++) acc[r][c] = (f32x4){0.f, 0.f, 0.f, 0.f};

    {
        bf16x8 af0 = *(const bf16x8*)&T[(wv * 32 + l16) * S + quad * 8];
        bf16x8 af1 = *(const bf16x8*)&T[(wv * 32 + 16 + l16) * S + quad * 8];
#pragma unroll
        for (int c = 0; c < 8; c++) {
            bf16x8 bfr = *(const bf16x8*)&Ws[((c * 64) + lane) * 8];
            acc[0][c] = MFMA16(af0, bfr, acc[0][c]);
            acc[1][c] = MFMA16(af1, bfr, acc[1][c]);
        }
    }

#pragma unroll
    for (int r = 0; r < 2; r++) {
        int mrow = wv * 32 + r * 16 + quad * 4;
#pragma unroll
        for (int c = 0; c < 8; c++) {
            int col = c * 16 + l16;
            float bb = bias[col];
#pragma unroll
            for (int q = 0; q < 4; q++)
                T[(mrow + q) * S + col] = (bf16_t)(acc[r][c][q] + bb);
        }
    }

#pragma unroll
    for (int it = 0; it < 8; ++it) {
        int idx = it * 64 + lane;
        int row = wv * 32 + (idx >> 4);
        int seg = idx & 15;
        long grow = row0 + row;
        if (grow < M)
            *(uint4*)&outp[grow * 128 + seg * 8] = *(const uint4*)&T[row * S + seg * 8];
    }
}

// ---------------------------------------------------------------------------
// Fused edge encoder, 64-row tiles, barrier-free wave-private flow.
// ---------------------------------------------------------------------------
__global__ __launch_bounds__(256) void edge_mlp_kernel(
    const float* __restrict__ A, int M,
    const bf16_t* __restrict__ Ws1, const float* __restrict__ b1,
    const bf16_t* __restrict__ Ws2, const float* __restrict__ b2,
    const int* __restrict__ eorig, bf16_t* __restrict__ outp)
{
    constexpr int S = 136;
    __shared__ bf16_t T[64 * S];

    const int  tid  = threadIdx.x;
    const int  wv   = tid >> 6, lane = tid & 63;
    const long row0 = (long)blockIdx.x * 64;
    const int  l16  = lane & 15, quad = lane >> 4;

    {
        int  r  = wv * 16 + (lane >> 2);
        long gr = row0 + r;
        float4 v = make_float4(0.f, 0.f, 0.f, 0.f);
        if (gr < M) {
            long eo = eorig[gr];
            v = *(const float4*)(A + eo * 16 + (lane & 3) * 4);
        }
        bf16_t* d = &T[r * S + (lane & 3) * 4];
        d[0] = (bf16_t)v.x; d[1] = (bf16_t)v.y; d[2] = (bf16_t)v.z; d[3] = (bf16_t)v.w;
    }

    f32x4 acc[8];
#pragma unroll
    for (int c = 0; c < 8; c++) acc[c] = (f32x4){0.f, 0.f, 0.f, 0.f};

    {   // stage 1: K=16
        bf16x8 af;
#pragma unroll
        for (int j = 0; j < 8; ++j) af[j] = (bf16_t)0.f;
        if (quad < 2) af = *(const bf16x8*)&T[(wv * 16 + l16) * S + quad * 8];
#pragma unroll
        for (int c = 0; c < 8; c++) {
            bf16x8 bfr = *(const bf16x8*)&Ws1[((c * 64) + lane) * 8];
            acc[c] = MFMA16(af, bfr, acc[c]);
        }
    }

    const int mbase = wv * 16 + quad * 4;

#pragma unroll
    for (int c = 0; c < 8; c++) {
        int col = c * 16 + l16;
        float bb = b1[col];
#pragma unroll
        for (int q = 0; q < 4; q++)
            T[(mbase + q) * S + col] = (bf16_t)fmaxf(acc[c][q] + bb, 0.f);
    }

#pragma unroll
    for (int c = 0; c < 8; c++) acc[c] = (f32x4){0.f, 0.f, 0.f, 0.f};

#pragma unroll
    for (int kc = 0; kc < 4; ++kc) {   // stage 2: K=128
        bf16x8 af = *(const bf16x8*)&T[(wv * 16 + l16) * S + kc * 32 + quad * 8];
#pragma unroll
        for (int c = 0; c < 8; c++) {
            bf16x8 bfr = *(const bf16x8*)&Ws2[(((kc * 8 + c) * 64) + lane) * 8];
            acc[c] = MFMA16(af, bfr, acc[c]);
        }
    }

#pragma unroll
    for (int c = 0; c < 8; c++) {
        int col = c * 16 + l16;
        float bb = b2[col];
#pragma unroll
        for (int q = 0; q < 4; q++)
            T[(mbase + q) * S + col] = (bf16_t)(acc[c][q] + bb);
    }

#pragma unroll
    for (int it = 0; it < 4; ++it) {
        int idx = it * 64 + lane;
        int row = wv * 16 + (idx >> 4);
        int seg = idx & 15;
        long grow = row0 + row;
        if (grow < M)
            *(uint4*)&outp[grow * 128 + seg * 8] = *(const uint4*)&T[row * S + seg * 8];
    }
}

// ---------------------------------------------------------------------------
// FUSED BN(+relu) + aggregation + GINEConv MLP, 64-node tiles.
// 512-thread blocks: wave pair (2t, 2t+1) gathers tile t (8 rows each,
// full-wave per row, 2 cols/lane) -> 2x resident waves, half the serial
// chain per wave. rowptr preloaded lane-parallel; next row's srcp chunk
// prefetched under current row's processing. Even wave does MFMA+epilogue.
// ---------------------------------------------------------------------------
template <int BN>
__global__ __launch_bounds__(512) void aggr_conv_kernel(
    const bf16_t* __restrict__ xin,
    const float* __restrict__ bns_prev,
    const float* __restrict__ gamma, const float* __restrict__ beta,
    const bf16_t* __restrict__ e,
    const int* __restrict__ rowptr, const int* __restrict__ srcp, int M,
    const bf16_t* __restrict__ Ws1, const float* __restrict__ b1,
    const bf16_t* __restrict__ Ws2, const float* __restrict__ b2,
    bf16_t* __restrict__ zout, float* __restrict__ bn_out)
{
    constexpr int S = 136;
    __shared__ bf16_t T[64 * S];

    const int  tid  = threadIdx.x;
    const int  wv   = tid >> 6, lane = tid & 63;
    const int  tw   = wv >> 1, sub = wv & 1;
    const long row0 = (long)blockIdx.x * 64;

    float sc0 = 1.f, sh0 = 0.f, sc1 = 1.f, sh1 = 0.f;
    if (BN) {
        const float invM = 1.f / (float)M;
        int c = lane * 2;
        float m0 = bns_prev[c] * invM;
        float v0 = bns_prev[128 + c] * invM - m0 * m0;
        float i0 = rsqrtf(v0 + 1e-5f);
        sc0 = gamma[c] * i0; sh0 = beta[c] - m0 * sc0;
        float m1 = bns_prev[c + 1] * invM;
        float v1 = bns_prev[128 + c + 1] * invM - m1 * m1;
        float i1 = rsqrtf(v1 + 1e-5f);
        sc1 = gamma[c + 1] * i1; sh1 = beta[c + 1] - m1 * sc1;
    }

    // --- preload this wave's 9 rowptr entries (rows nbase..nbase+8) ---
    const long nbase = row0 + tw * 16 + sub * 8;
    int rpv = 0;
    {
        long idx = nbase + lane;
        if (idx > M) idx = M;
        if (lane <= 8) rpv = rowptr[idx];
    }

    // prefetch first row's first srcp chunk
    int sv;
    {
        int b0 = __shfl(rpv, 0), e0 = __shfl(rpv, 1);
        sv = (b0 + lane < e0) ? srcp[b0 + lane] : 0;
    }

    // --- gather: 8 rows per wave, full wave per row, 2 cols/lane ---
#pragma unroll 1
    for (int r8 = 0; r8 < 8; ++r8) {
        const int  r   = tw * 16 + sub * 8 + r8;
        const long n   = row0 + r;
        const int  beg = __shfl(rpv, r8);
        const int  end = __shfl(rpv, r8 + 1);
        int svc = sv;
        if (r8 < 7) {   // prefetch next row's first chunk
            int nb = __shfl(rpv, r8 + 1), ne = __shfl(rpv, r8 + 2);
            sv = (nb + lane < ne) ? srcp[nb + lane] : 0;
        }
        float ax = 0.f, ay = 0.f;
        if (n < M) {
            bf16x2 xv = *(const bf16x2*)(xin + n * 128 + lane * 2);
            ax = BN ? fmaxf((float)xv[0] * sc0 + sh0, 0.f) : (float)xv[0];
            ay = BN ? fmaxf((float)xv[1] * sc1 + sh1, 0.f) : (float)xv[1];
            for (int base = beg; base < end; base += 64) {
                int cnt = min(64, end - base);
                int svv = (base == beg) ? svc
                                        : ((base + lane < end) ? srcp[base + lane] : 0);
                int j = 0;
                for (; j + 3 < cnt; j += 4) {
                    int s0 = __shfl(svv, j),     s1 = __shfl(svv, j + 1);
                    int s2 = __shfl(svv, j + 2), s3 = __shfl(svv, j + 3);
                    bf16x2 x0 = *(const bf16x2*)(xin + (long)s0 * 128 + lane * 2);
                    bf16x2 x1 = *(const bf16x2*)(xin + (long)s1 * 128 + lane * 2);
                    bf16x2 x2 = *(const bf16x2*)(xin + (long)s2 * 128 + lane * 2);
                    bf16x2 x3 = *(const bf16x2*)(xin + (long)s3 * 128 + lane * 2);
                    bf16x2 e0 = *(const bf16x2*)(e + (long)(base + j + 0) * 128 + lane * 2);
                    bf16x2 e1 = *(const bf16x2*)(e + (long)(base + j + 1) * 128 + lane * 2);
                    bf16x2 e2 = *(const bf16x2*)(e + (long)(base + j + 2) * 128 + lane * 2);
                    bf16x2 e3 = *(const bf16x2*)(e + (long)(base + j + 3) * 128 + lane * 2);
                    float hx, hy;
                    hx = BN ? fmaxf((float)x0[0] * sc0 + sh0, 0.f) : (float)x0[0];
                    hy = BN ? fmaxf((float)x0[1] * sc1 + sh1, 0.f) : (float)x0[1];
                    ax += fmaxf(hx + (float)e0[0], 0.f);
                    ay += fmaxf(hy + (float)e0[1], 0.f);
                    hx = BN ? fmaxf((float)x1[0] * sc0 + sh0, 0.f) : (float)x1[0];
                    hy = BN ? fmaxf((float)x1[1] * sc1 + sh1, 0.f) : (float)x1[1];
                    ax += fmaxf(hx + (float)e1[0], 0.f);
                    ay += fmaxf(hy + (float)e1[1], 0.f);
                    hx = BN ? fmaxf((float)x2[0] * sc0 + sh0, 0.f) : (float)x2[0];
                    hy = BN ? fmaxf((float)x2[1] * sc1 + sh1, 0.f) : (float)x2[1];
                    ax += fmaxf(hx + (float)e2[0], 0.f);
                    ay += fmaxf(hy + (float)e2[1], 0.f);
                    hx = BN ? fmaxf((float)x3[0] * sc0 + sh0, 0.f) : (float)x3[0];
                    hy = BN ? fmaxf((float)x3[1] * sc1 + sh1, 0.f) : (float)x3[1];
                    ax += fmaxf(hx + (float)e3[0], 0.f);
                    ay += fmaxf(hy + (float)e3[1], 0.f);
                }
                for (; j < cnt; ++j) {
                    int s0 = __shfl(svv, j);
                    bf16x2 x0 = *(const bf16x2*)(xin + (long)s0 * 128 + lane * 2);
                    bf16x2 e0 = *(const bf16x2*)(e + (long)(base + j) * 128 + lane * 2);
                    float hx = BN ? fmaxf((float)x0[0] * sc0 + sh0, 0.f) : (float)x0[0];
                    float hy = BN ? fmaxf((float)x0[1] * sc1 + sh1, 0.f) : (float)x0[1];
                    ax += fmaxf(hx + (float)e0[0], 0.f);
                    ay += fmaxf(hy + (float)e0[1], 0.f);
                }
            }
        }
        bf16x2 o; o[0] = (bf16_t)ax; o[1] = (bf16_t)ay;
        *(bf16x2*)&T[r * S + lane * 2] = o;
    }
    __syncthreads();

    // --- MFMA + epilogue: even wave of each pair handles its tile ---
    if (sub == 0) {
        const int l16 = lane & 15, quad = lane >> 4;
        const int mbase = tw * 16 + quad * 4;

        f32x4 acc[8];
#pragma unroll
        for (int c = 0; c < 8; c++) acc[c] = (f32x4){0.f, 0.f, 0.f, 0.f};

#pragma unroll
        for (int kc = 0; kc < 4; ++kc) {
            bf16x8 af = *(const bf16x8*)&T[(tw * 16 + l16) * S + kc * 32 + quad * 8];
#pragma unroll
            for (int c = 0; c < 8; c++) {
                bf16x8 bfr = *(const bf16x8*)&Ws1[(((kc * 8 + c) * 64) + lane) * 8];
                acc[c] = MFMA16(af, bfr, acc[c]);
            }
        }

#pragma unroll
        for (int c = 0; c < 8; c++) {
            int col = c * 16 + l16;
            float bb = b1[col];
#pragma unroll
            for (int q = 0; q < 4; q++)
                T[(mbase + q) * S + col] = (bf16_t)fmaxf(acc[c][q] + bb, 0.f);
        }

#pragma unroll
        for (int c = 0; c < 8; c++) acc[c] = (f32x4){0.f, 0.f, 0.f, 0.f};

#pragma unroll
        for (int kc = 0; kc < 4; ++kc) {
            bf16x8 af = *(const bf16x8*)&T[(tw * 16 + l16) * S + kc * 32 + quad * 8];
#pragma unroll
            for (int c = 0; c < 8; c++) {
                bf16x8 bfr = *(const bf16x8*)&Ws2[(((kc * 8 + c) * 64) + lane) * 8];
                acc[c] = MFMA16(af, bfr, acc[c]);
            }
        }

        float ssum[8], ssq[8];
#pragma unroll
        for (int c = 0; c < 8; c++) {
            int col = c * 16 + l16;
            float bb = b2[col];
            float s = 0.f, s2 = 0.f;
#pragma unroll
            for (int q = 0; q < 4; q++) {
                float v = acc[c][q] + bb;
                T[(mbase + q) * S + col] = (bf16_t)v;
                if (row0 + mbase + q < M) { s += v; s2 += v * v; }
            }
            s  += __shfl_xor(s, 16);  s  += __shfl_xor(s, 32);
            s2 += __shfl_xor(s2, 16); s2 += __shfl_xor(s2, 32);
            ssum[c] = s; ssq[c] = s2;
        }

#pragma unroll
        for (int it = 0; it < 4; ++it) {
            int idx = it * 64 + lane;
            int row = tw * 16 + (idx >> 4);
            int seg = idx & 15;
            long grow = row0 + row;
            if (grow < M)
                *(uint4*)&zout[grow * 128 + seg * 8] = *(const uint4*)&T[row * S + seg * 8];
        }

        float* wred = (float*)&T[(size_t)(tw * 16) * S];
        if (quad == 0) {
#pragma unroll
            for (int c = 0; c < 8; c++) {
                int col = c * 16 + l16;
                wred[col]       = ssum[c];
                wred[128 + col] = ssq[c];
            }
        }
    }
    __syncthreads();
    if (tid < 128) {
        float s = 0.f, s2 = 0.f;
#pragma unroll
        for (int w = 0; w < 4; ++w) {
            const float* wr = (const float*)&T[(size_t)(w * 16) * S];
            s  += wr[tid];
            s2 += wr[128 + tid];
        }
        atomicAdd(&bn_out[tid], s);
        atomicAdd(&bn_out[128 + tid], s2);
    }
}

// ---------------------------------------------------------------------------
// Mean-pool over sorted batch; derives final-layer BN inline.
// ---------------------------------------------------------------------------
__global__ __launch_bounds__(128) void pool_kernel(
    const bf16_t* __restrict__ z, const float* __restrict__ bns,
    const float* __restrict__ gamma, const float* __restrict__ beta,
    const int* __restrict__ batch,
    float* __restrict__ gsum, float* __restrict__ cnt, int N)
{
    int c = threadIdx.x;
    float mean = bns[c] / (float)N;
    float var  = bns[128 + c] / (float)N - mean * mean;
    float inv  = rsqrtf(var + 1e-5f);
    float sc   = gamma[c] * inv;
    float sh   = beta[c] - mean * sc;
    int n0 = blockIdx.x * 32;
    int n1 = min(n0 + 32, N);
    float acc = 0.f;
    int cur = -1, rc = 0;
    for (int n = n0; n < n1; ++n) {
        int g = batch[n];
        if (g != cur) {
            if (cur >= 0) {
                atomicAdd(&gsum[(long)cur * 128 + c], acc);
                if (c == 0) atomicAdd(&cnt[cur], (float)rc);
            }
            cur = g; acc = 0.f; rc = 0;
        }
        acc += fmaxf((float)z[(long)n * 128 + c] * sc + sh, 0.f);
        rc++;
    }
    if (cur >= 0) {
        atomicAdd(&gsum[(long)cur * 128 + c], acc);
        if (c == 0) atomicAdd(&cnt[cur], (float)rc);
    }
}

__global__ __launch_bounds__(128) void head_kernel(
    const float* __restrict__ gsum, const float* __restrict__ cnt,
    const float* __restrict__ ext_in,
    const float* __restrict__ ew1, const float* __restrict__ eb1,
    const float* __restrict__ ew2, const float* __restrict__ eb2,
    const float* __restrict__ rw1, const float* __restrict__ rb1,
    const float* __restrict__ rw2, const float* __restrict__ rb2,
    float* __restrict__ out)
{
    int g = blockIdx.x, c = threadIdx.x;
    __shared__ float sx[8];
    __shared__ float h1[128];
    __shared__ float comb[256];
    __shared__ float red[128];

    if (c < 8) sx[c] = ext_in[g * 8 + c];
    __syncthreads();
    float a = eb1[c];
#pragma unroll
    for (int k = 0; k < 8; k++) a += sx[k] * ew1[k * 128 + c];
    h1[c] = fmaxf(a, 0.f);
    __syncthreads();
    float b = eb2[c];
    for (int k = 0; k < 128; k++) b += h1[k] * ew2[k * 128 + c];
    comb[c]       = gsum[(long)g * 128 + c] / fmaxf(cnt[g], 1.0f);
    comb[128 + c] = b;
    __syncthreads();
    float r = rb1[c];
    for (int k = 0; k < 256; k++) r += comb[k] * rw1[k * 128 + c];
    r = fmaxf(r, 0.f);
    red[c] = r * rw2[c];
    __syncthreads();
    if (c == 0) {
        float s = rb2[0];
        for (int k = 0; k < 128; k++) s += red[k];
        out[g] = s;
    }
}

// ---------------------------------------------------------------------------
extern "C" void kernel_launch(void* const* d_in, const int* in_sizes, int n_in,
                              void* d_out, int out_size, void* d_ws, size_t ws_size,
                              hipStream_t stream)
{
    const float* x         = (const float*)d_in[0];
    const float* edge_attr = (const float*)d_in[1];
    const float* externals = (const float*)d_in[2];
    const float* node_w    = (const float*)d_in[3];
    const float* node_b    = (const float*)d_in[4];
    const float* ee_w1     = (const float*)d_in[5];
    const float* ee_b1     = (const float*)d_in[6];
    const float* ee_w2     = (const float*)d_in[7];
    const float* ee_b2     = (const float*)d_in[8];
    const float* conv_w1   = (const float*)d_in[9];
    const float* conv_b1   = (const float*)d_in[10];
    const float* conv_w2   = (const float*)d_in[11];
    const float* conv_b2   = (const float*)d_in[12];
    const float* bn_gamma  = (const float*)d_in[13];
    const float* bn_beta   = (const float*)d_in[14];
    const float* ext_w1    = (const float*)d_in[15];
    const float* ext_b1    = (const float*)d_in[16];
    const float* ext_w2    = (const float*)d_in[17];
    const float* ext_b2    = (const float*)d_in[18];
    const float* reg_w1    = (const float*)d_in[19];
    const float* reg_b1    = (const float*)d_in[20];
    const float* reg_w2    = (const float*)d_in[21];
    const float* reg_b2    = (const float*)d_in[22];
    const int* edge_index  = (const int*)d_in[23];
    const int* batch       = (const int*)d_in[24];

    const int N = in_sizes[0] / 32;
    const int E = in_sizes[1] / 16;
    const int G = in_sizes[2] / 8;
    const int NB = (N + 1023) / 1024;

    char* p = (char*)d_ws;
    auto alloc = [&](size_t bytes) -> void* {
        void* r = (void*)p;
        p += (bytes + 255) & ~(size_t)255;
        return r;
    };
    bf16_t* h       = (bf16_t*)alloc((size_t)N * 128 * 2);
    bf16_t* zA      = (bf16_t*)alloc((size_t)N * 128 * 2);
    bf16_t* zB      = (bf16_t*)alloc((size_t)N * 128 * 2);
    bf16_t* ebuf    = (bf16_t*)alloc((size_t)E * 128 * 2);   // dst-sorted
    int*    deg     = (int*)alloc((size_t)N * 4);
    int*    rowptr  = (int*)alloc(((size_t)N + 1) * 4);
    int*    cursor  = (int*)alloc((size_t)N * 4);
    int*    partials= (int*)alloc((size_t)N * 4);
    int*    bsums   = (int*)alloc((size_t)NB * 4);
    int*    boff    = (int*)alloc((size_t)NB * 4);
    int*    srcp    = (int*)alloc((size_t)E * 4);
    int*    eorig   = (int*)alloc((size_t)E * 4);
    bf16_t* node_wt = (bf16_t*)alloc(128 * 32 * 2);
    bf16_t* ee_w1t  = (bf16_t*)alloc(128 * 32 * 2);
    bf16_t* ee_w2t  = (bf16_t*)alloc(128 * 128 * 2);
    bf16_t* cw1t    = (bf16_t*)alloc(3 * 128 * 128 * 2);
    bf16_t* cw2t    = (bf16_t*)alloc(3 * 128 * 128 * 2);
    float*  bns     = (float*)alloc(3 * 256 * 4);            // per-layer BN sums
    float*  gsum    = (float*)alloc((size_t)G * 128 * 4);
    float*  cnt     = (float*)alloc((size_t)G * 4);

    // --- CSR build (by dst); hist also warms edge_attr into MALL ---
    hipMemsetAsync(deg, 0, (size_t)N * 4, stream);
    hipMemsetAsync(bns, 0, 3 * 256 * 4, stream);
    hist_kernel<<<(E + 255) / 256, 256, 0, stream>>>(edge_index, deg, E, edge_attr);
    scanA_kernel<<<NB, 256, 0, stream>>>(deg, partials, bsums, N);
    scanB_kernel<<<1, 256, 0, stream>>>(bsums, boff, rowptr, NB, N);
    scanC_kernel<<<(N + 255) / 256, 256, 0, stream>>>(partials, boff, rowptr, cursor, N);
    scatter_kernel<<<(E + 255) / 256, 256, 0, stream>>>(edge_index, cursor, srcp, eorig, E);

    // --- weight prep (single launch) ---
    prep_all_kernel<<<480, 256, 0, stream>>>(node_w, ee_w1, ee_w2, conv_w1, conv_w2,
                                             node_wt, ee_w1t, ee_w2t, cw1t, cw2t);

    // --- node encoder ---
    node_enc_kernel<<<(N + 127) / 128, 256, 0, stream>>>(x, N, node_wt, node_b, h);

    // --- edge encoder, CSR-order compute, sequential write ---
    edge_mlp_kernel<<<(E + 63) / 64, 256, 0, stream>>>(
        edge_attr, E, ee_w1t, ee_b1, ee_w2t, ee_b2, eorig, ebuf);

    // --- GINE layers: BN folded into the gather of the next consumer ---
    const int nblk = (N + 63) / 64;
    aggr_conv_kernel<0><<<nblk, 512, 0, stream>>>(
        h, nullptr, nullptr, nullptr, ebuf, rowptr, srcp, N,
        cw1t + 0 * 16384, conv_b1 + 0 * 128, cw2t + 0 * 16384, conv_b2 + 0 * 128,
        zA, bns + 0);
    aggr_conv_kernel<1><<<nblk, 512, 0, stream>>>(
        zA, bns + 0, bn_gamma + 0, bn_beta + 0, ebuf, rowptr, srcp, N,
        cw1t + 1 * 16384, conv_b1 + 1 * 128, cw2t + 1 * 16384, conv_b2 + 1 * 128,
        zB, bns + 256);
    aggr_conv_kernel<1><<<nblk, 512, 0, stream>>>(
        zB, bns + 256, bn_gamma + 128, bn_beta + 128, ebuf, rowptr, srcp, N,
        cw1t + 2 * 16384, conv_b1 + 2 * 128, cw2t + 2 * 16384, conv_b2 + 2 * 128,
        zA, bns + 512);

    // --- pooling (BN+relu applied on read) + head ---
    hipMemsetAsync(gsum, 0, (size_t)G * 128 * 4, stream);
    hipMemsetAsync(cnt, 0, (size_t)G * 4, stream);
    pool_kernel<<<(N + 31) / 32, 128, 0, stream>>>(zA, bns + 512, bn_gamma + 256, bn_beta + 256,
                                                   batch, gsum, cnt, N);
    head_kernel<<<G, 128, 0, stream>>>(gsum, cnt, externals,
                                       ext_w1, ext_b1, ext_w2, ext_b2,
                                       reg_w1, reg_b1, reg_w2, reg_b2,
                                       (float*)d_out);
}